// Round 5
// baseline (264.333 us; speedup 1.0000x reference)
//
#include <hip/hip_runtime.h>
#include <hip/hip_bf16.h>
#include <math.h>

// MoLE layer: out = gelu(x @ base_w^T + base_b) + top1_w * (gelu(x @ A[e]) @ B[e])
// probs = softmax(x @ gate_w^T + gate_b)
// T=8192 tokens, D=2048, E=8 experts, RANK=16.
//
// Pipeline (3 kernels):
//  k1 prep:  LDS-tiled transposes lora_B -> Bt[j][e*16+r], lora_A -> Ab[e*16+r][k]
//            (K-major bf16 MFMA operands). Dependency-free, tiny (384 blocks).
//  k2 fused: token blocks (32 tok each) do EVERYTHING per-token in one block:
//            cvt x->Xb bf16, exact-fp32 logits/softmax/argmax (gate_w in regs),
//            probs out, then H = Xb_tile @ Ab^T via MFMA (BK=64, staged from the
//            block's own L2-hot Xb writes + Ab), epilogue writes one-hot
//            A2[t][e*16+r] = (idx==e)*w*gelu(H). Other blocks convert base_w.
//  k3 gemm:  128x128 bf16 MFMA GEMM, BK=64, 8-slot XOR-swizzled LDS
//            (conflict-free ds_read_b128), m-fastest grid (R3 order: 70 MB fetch
//            vs 151 MB for n-fastest). Epilogue: +bias, GELU, LoRA as 4 extra
//            K=32 MFMAs from A2/Bt, store fp32.

#define DIM   2048
#define RANK  16
#define NEXP  8
#define NTOK  8192
#define KLORA 128   // NEXP*RANK

typedef __hip_bfloat16 bf16;
typedef __attribute__((ext_vector_type(8))) short short8;  // 8 bf16 = 4 VGPRs
typedef __attribute__((ext_vector_type(4))) float float4v;

typedef const __attribute__((address_space(1))) void* gptr_t;
typedef __attribute__((address_space(3))) void*       sptr_t;

__device__ __forceinline__ void async_ld16(const bf16* g, bf16* l) {
    __builtin_amdgcn_global_load_lds((gptr_t)g, (sptr_t)l, 16, 0, 0);
}

// tanh-approx GELU: |err vs erf-gelu| <= ~3e-3, well under 0.1 threshold
__device__ __forceinline__ float gelu_fast(float x) {
    float t = 0.7978845608028654f * (x + 0.044715f * x * x * x);
    t = fminf(fmaxf(t, -10.0f), 10.0f);
    float e = __expf(2.0f * t);
    float th = (e - 1.0f) / (e + 1.0f);
    return 0.5f * x * (1.0f + th);
}

__device__ __forceinline__ short8 pack8(float4 v0, float4 v1) {
    union { bf16 h[8]; short8 v; } u;
    u.h[0] = __float2bfloat16(v0.x); u.h[1] = __float2bfloat16(v0.y);
    u.h[2] = __float2bfloat16(v0.z); u.h[3] = __float2bfloat16(v0.w);
    u.h[4] = __float2bfloat16(v1.x); u.h[5] = __float2bfloat16(v1.y);
    u.h[6] = __float2bfloat16(v1.z); u.h[7] = __float2bfloat16(v1.w);
    return u.v;
}

// ---------------------------------------------------------------- prep kernel
// blocks [0,256): Bt transpose (32x32 tiles). [256,384): Ab transpose.
__global__ __launch_bounds__(256) void prep_kernel(
    const float* __restrict__ lora_B, const float* __restrict__ lora_A,
    bf16* __restrict__ Bt, bf16* __restrict__ Ab)
{
    __shared__ float buf[2560];
    const int b   = blockIdx.x;
    const int tid = threadIdx.x;

    if (b < 256) {
        // ---- Bt transpose: lora_B [128][2048] -> Bt [2048][128], 32x32 tile
        int kk0 = (b >> 6) * 32, j0 = (b & 63) * 32;
        {   // read coalesced along j
            int r = tid >> 3, c4 = (tid & 7) * 4;
            float4 val = *(const float4*)(lora_B + (size_t)(kk0 + r) * DIM + j0 + c4);
            *(float4*)(buf + r * 36 + c4) = val;
        }
        __syncthreads();
        {   // write coalesced along kk
            int j = tid >> 3, k4 = (tid & 7) * 4;
            bf16* dst = Bt + (size_t)(j0 + j) * KLORA + kk0 + k4;
            #pragma unroll
            for (int i = 0; i < 4; i++) dst[i] = __float2bfloat16(buf[(k4 + i) * 36 + j]);
        }
    } else {
        // ---- Ab transpose: lora_A [8][2048][16] -> Ab [128][2048]
        int bb = b - 256;
        int e = bb >> 4, k0 = (bb & 15) * 128;
        const float* src = lora_A + (size_t)e * DIM * RANK;
        {
            int k = tid >> 2, r4 = (tid & 3) * 4;
            float4 va = *(const float4*)(src + (size_t)(k0 + k) * RANK + r4);
            float4 vb = *(const float4*)(src + (size_t)(k0 + k + 64) * RANK + r4);
            *(float4*)(buf + k * 20 + r4)        = va;
            *(float4*)(buf + (k + 64) * 20 + r4) = vb;
        }
        __syncthreads();
        {
            int r = tid >> 4, kx = (tid & 15) * 8;
            bf16* dst = Ab + (size_t)(e * 16 + r) * DIM + k0 + kx;
            #pragma unroll
            for (int i = 0; i < 8; i++) dst[i] = __float2bfloat16(buf[(kx + i) * 20 + r]);
        }
    }
}

// --------------------------------------------------------------- fused kernel
// blocks [0,256): 32 tokens each -> cvt + logits + H-MFMA + one-hot A2.
// blocks [256,2304): base_w cvt.
__global__ __launch_bounds__(256, 4) void fused_kernel(
    const float* __restrict__ x, const float* __restrict__ gate_w,
    const float* __restrict__ gate_b, const float* __restrict__ base_w,
    const bf16* __restrict__ Ab,
    bf16* __restrict__ Xb, bf16* __restrict__ Wb, bf16* __restrict__ A2,
    float* __restrict__ probs)
{
    const int b   = blockIdx.x;
    const int tid = threadIdx.x;

    if (b < 256) {
        __shared__ bf16  Xs[32 * 64];        //  4 KB
        __shared__ bf16  Las[128 * 64];      // 16 KB
        __shared__ float lgbuf[32 * 32];     //  4 KB
        __shared__ float wtok[32];
        __shared__ int   etok[32];

        const int t0   = b * 32;
        const int wave = tid >> 6, lane = tid & 63;

        // ---- phase 1: cvt + fp32 logit partials (gate_w in registers) ----
        float4 g0[NEXP], g1[NEXP];
        #pragma unroll
        for (int e = 0; e < NEXP; e++) {
            const float* wr = gate_w + (size_t)e * DIM + tid * 8;
            g0[e] = *(const float4*)wr;
            g1[e] = *(const float4*)(wr + 4);
        }
        for (int tt = 0; tt < 32; tt++) {
            const int t = t0 + tt;
            const float* xr = x + (size_t)t * DIM + tid * 8;
            float4 v0 = *(const float4*)xr;
            float4 v1 = *(const float4*)(xr + 4);
            *(short8*)(Xb + (size_t)t * DIM + tid * 8) = pack8(v0, v1);
            float a[NEXP];
            #pragma unroll
            for (int e = 0; e < NEXP; e++) {
                a[e] = v0.x * g0[e].x + v0.y * g0[e].y + v0.z * g0[e].z + v0.w * g0[e].w
                     + v1.x * g1[e].x + v1.y * g1[e].y + v1.z * g1[e].z + v1.w * g1[e].w;
                #pragma unroll
                for (int off = 32; off > 0; off >>= 1) a[e] += __shfl_down(a[e], off);
            }
            if (lane == 0) {
                #pragma unroll
                for (int e = 0; e < NEXP; e++) lgbuf[tt * 32 + wave * NEXP + e] = a[e];
            }
        }
        __syncthreads();
        if (tid < 32) {                      // finalize token t0+tid
            const int t = t0 + tid;
            float l[NEXP]; float mx = -1e30f;
            #pragma unroll
            for (int e = 0; e < NEXP; e++) {
                l[e] = lgbuf[tid * 32 + e] + lgbuf[tid * 32 + 8 + e]
                     + lgbuf[tid * 32 + 16 + e] + lgbuf[tid * 32 + 24 + e] + gate_b[e];
                mx = fmaxf(mx, l[e]);
            }
            float sum = 0.f;
            #pragma unroll
            for (int e = 0; e < NEXP; e++) { l[e] = __expf(l[e] - mx); sum += l[e]; }
            float inv = 1.0f / sum;
            int es = 0; float best = l[0];
            #pragma unroll
            for (int e = 1; e < NEXP; e++) if (l[e] > best) { best = l[e]; es = e; }
            #pragma unroll
            for (int e = 0; e < NEXP; e++) probs[(size_t)t * NEXP + e] = l[e] * inv;
            etok[tid] = es;
            wtok[tid] = best * inv;
        }

        // ---- phase 2: H = Xb[t0:t0+32] @ Ab^T (M=32, N=128, K=2048, BK=64) ----
        const int col = lane & 15, quad = lane >> 4;
        const int kc  = ((tid & 7) ^ ((tid >> 3) & 7)) * 8;
        const int row = tid >> 3;            // 0..31
        const bf16* gX = Xb + (size_t)(t0 + row) * DIM + kc;   // L2-hot (own writes)
        const bf16* gL = Ab + (size_t)row * DIM + kc;
        bf16* lX = Xs  + wave * 512;
        bf16* lL = Las + wave * 512;

        const int sl0 = (quad       ^ (col & 7)) * 8;
        const int sl1 = ((quad | 4) ^ (col & 7)) * 8;
        const bf16* pa = Xs  + col * 64;                 // + i*1024
        const bf16* pb = Las + (wave * 32 + col) * 64;   // + jt*1024

        float4v acc[2][2] = {};
        for (int k0 = 0; k0 < DIM; k0 += 64) {
            __syncthreads();
            async_ld16(gX + k0, lX);
            async_ld16(gL + k0,                        lL);
            async_ld16(gL + (size_t)32 * DIM + k0,     lL + 2048);
            async_ld16(gL + (size_t)64 * DIM + k0,     lL + 4096);
            async_ld16(gL + (size_t)96 * DIM + k0,     lL + 6144);
            __syncthreads();
            #pragma unroll
            for (int ks = 0; ks < 2; ks++) {
                const int sl = ks ? sl1 : sl0;
                short8 a0 = *(const short8*)(pa + sl);
                short8 a1 = *(const short8*)(pa + 1024 + sl);
                short8 b0 = *(const short8*)(pb + sl);
                short8 b1 = *(const short8*)(pb + 1024 + sl);
                acc[0][0] = __builtin_amdgcn_mfma_f32_16x16x32_bf16(a0, b0, acc[0][0], 0, 0, 0);
                acc[0][1] = __builtin_amdgcn_mfma_f32_16x16x32_bf16(a0, b1, acc[0][1], 0, 0, 0);
                acc[1][0] = __builtin_amdgcn_mfma_f32_16x16x32_bf16(a1, b0, acc[1][0], 0, 0, 0);
                acc[1][1] = __builtin_amdgcn_mfma_f32_16x16x32_bf16(a1, b1, acc[1][1], 0, 0, 0);
            }
        }

        // ---- epilogue: one-hot A2 (C/D: row = quad*4+reg, col = lane&15) ----
        #pragma unroll
        for (int i = 0; i < 2; i++) {
            #pragma unroll
            for (int jt = 0; jt < 2; jt++) {
                const int jcol = wave * 32 + jt * 16 + col;
                const int ej   = jcol >> 4;
                #pragma unroll
                for (int r = 0; r < 4; r++) {
                    const int tl = i * 16 + quad * 4 + r;
                    float v = (etok[tl] == ej) ? gelu_fast(acc[i][jt][r]) * wtok[tl] : 0.0f;
                    A2[(size_t)(t0 + tl) * KLORA + jcol] = __float2bfloat16(v);
                }
            }
        }
    } else {
        // ---- base_w convert: 8 floats/thread ----
        size_t v = ((size_t)(b - 256) * 256 + tid) * 8;
        float4 v0 = *(const float4*)(base_w + v);
        float4 v1 = *(const float4*)(base_w + v + 4);
        *(short8*)(Wb + v) = pack8(v0, v1);
    }
}

// --------------------------------------------------------------- GEMM kernel
// BK=64 staging (32 barrier rounds), two K=32 MFMA passes per staged buffer.
__global__ __launch_bounds__(256, 3) void gemm_kernel(
    const bf16* __restrict__ Xb, const bf16* __restrict__ Wb,
    const float* __restrict__ base_b,
    const bf16* __restrict__ A2, const bf16* __restrict__ Bt,
    float* __restrict__ out)
{
    __shared__ bf16 As[128 * 64];   // 16 KB
    __shared__ bf16 Bs[128 * 64];   // 16 KB
    const int tid  = threadIdx.x;
    const int wave = tid >> 6, lane = tid & 63;
    const int wm = wave >> 1, wn = wave & 1;
    const int m0 = blockIdx.x * 128;    // m fastest (R3 order: 70 MB fetch)
    const int n0 = blockIdx.y * 128;
    const int col = lane & 15, quad = lane >> 4;

    const int kc = (((tid & 7) ^ ((tid >> 3) & 7))) * 8;
    const int r0 = tid >> 3;            // 0..31
    const bf16* gA0 = Xb + (size_t)(m0 + r0) * DIM + kc;
    const bf16* gB0 = Wb + (size_t)(n0 + r0) * DIM + kc;
    const bf16* gA1 = gA0 + (size_t)32 * DIM;
    const bf16* gB1 = gB0 + (size_t)32 * DIM;
    const bf16* gA2 = gA0 + (size_t)64 * DIM;
    const bf16* gB2 = gB0 + (size_t)64 * DIM;
    const bf16* gA3 = gA0 + (size_t)96 * DIM;
    const bf16* gB3 = gB0 + (size_t)96 * DIM;
    bf16* lA = As + wave * 512;
    bf16* lB = Bs + wave * 512;

    const int sl0 = (quad        ^ (col & 7)) * 8;
    const int sl1 = ((quad | 4)  ^ (col & 7)) * 8;
    const bf16* paA = As + (wm * 64 + col) * 64;
    const bf16* pbB = Bs + (wn * 64 + col) * 64;

    float4v acc[4][4] = {};

    for (int k0 = 0; k0 < DIM; k0 += 64) {
        __syncthreads();
        async_ld16(gA0 + k0, lA);
        async_ld16(gA1 + k0, lA + 2048);
        async_ld16(gA2 + k0, lA + 4096);
        async_ld16(gA3 + k0, lA + 6144);
        async_ld16(gB0 + k0, lB);
        async_ld16(gB1 + k0, lB + 2048);
        async_ld16(gB2 + k0, lB + 4096);
        async_ld16(gB3 + k0, lB + 6144);
        __syncthreads();
        {   // K-step 0
            short8 a[4], b[4];
            #pragma unroll
            for (int i = 0; i < 4; i++) a[i] = *(const short8*)(paA + i * 1024 + sl0);
            #pragma unroll
            for (int j = 0; j < 4; j++) b[j] = *(const short8*)(pbB + j * 1024 + sl0);
            #pragma unroll
            for (int i = 0; i < 4; i++)
                #pragma unroll
                for (int j = 0; j < 4; j++)
                    acc[i][j] = __builtin_amdgcn_mfma_f32_16x16x32_bf16(
                        a[i], b[j], acc[i][j], 0, 0, 0);
        }
        {   // K-step 1
            short8 a[4], b[4];
            #pragma unroll
            for (int i = 0; i < 4; i++) a[i] = *(const short8*)(paA + i * 1024 + sl1);
            #pragma unroll
            for (int j = 0; j < 4; j++) b[j] = *(const short8*)(pbB + j * 1024 + sl1);
            #pragma unroll
            for (int i = 0; i < 4; i++)
                #pragma unroll
                for (int j = 0; j < 4; j++)
                    acc[i][j] = __builtin_amdgcn_mfma_f32_16x16x32_bf16(
                        a[i], b[j], acc[i][j], 0, 0, 0);
        }
    }

    // epilogue 1: bias + GELU
    float bias[4];
    #pragma unroll
    for (int j = 0; j < 4; j++) bias[j] = base_b[n0 + wn * 64 + j * 16 + col];
    #pragma unroll
    for (int i = 0; i < 4; i++)
        #pragma unroll
        for (int j = 0; j < 4; j++)
            #pragma unroll
            for (int r = 0; r < 4; r++)
                acc[i][j][r] = gelu_fast(acc[i][j][r] + bias[j]);

    // epilogue 2: LoRA as K=128 MFMA extension (4 steps of K=32)
    const bf16* pea = A2 + (size_t)(m0 + wm * 64 + col) * KLORA + quad * 8;
    const bf16* peb = Bt + (size_t)(n0 + wn * 64 + col) * KLORA + quad * 8;
    #pragma unroll
    for (int ks = 0; ks < 4; ks++) {
        short8 ea[4], eb[4];
        #pragma unroll
        for (int i = 0; i < 4; i++)
            ea[i] = *(const short8*)(pea + i * 16 * KLORA + ks * 32);
        #pragma unroll
        for (int j = 0; j < 4; j++)
            eb[j] = *(const short8*)(peb + j * 16 * KLORA + ks * 32);
        #pragma unroll
        for (int i = 0; i < 4; i++)
            #pragma unroll
            for (int j = 0; j < 4; j++)
                acc[i][j] = __builtin_amdgcn_mfma_f32_16x16x32_bf16(
                    ea[i], eb[j], acc[i][j], 0, 0, 0);
    }

    // store fp32
    #pragma unroll
    for (int i = 0; i < 4; i++) {
        #pragma unroll
        for (int j = 0; j < 4; j++) {
            int tt = m0 + wm * 64 + i * 16 + quad * 4;
            int jj = n0 + wn * 64 + j * 16 + col;
            float* po = out + (size_t)tt * DIM + jj;
            #pragma unroll
            for (int r = 0; r < 4; r++) po[(size_t)r * DIM] = acc[i][j][r];
        }
    }
}

// ------------------------------------------------------------------- launch
extern "C" void kernel_launch(void* const* d_in, const int* in_sizes, int n_in,
                              void* d_out, int out_size, void* d_ws, size_t ws_size,
                              hipStream_t stream)
{
    (void)in_sizes; (void)n_in; (void)out_size; (void)ws_size;
    const float* x      = (const float*)d_in[0];
    const float* gate_w = (const float*)d_in[1];
    const float* gate_b = (const float*)d_in[2];
    const float* base_w = (const float*)d_in[3];
    const float* base_b = (const float*)d_in[4];
    const float* lora_A = (const float*)d_in[5];
    const float* lora_B = (const float*)d_in[6];

    float* out   = (float*)d_out;                    // [8192, 2048]
    float* probs = out + (size_t)NTOK * DIM;         // [8192, 8]

    // workspace layout (~45.1 MB)
    char* ws = (char*)d_ws;
    bf16*  Xb   = (bf16*)ws;                          // 33,554,432 B
    bf16*  Wb   = (bf16*)(ws + 33554432);             //  8,388,608 B
    bf16*  A2   = (bf16*)(ws + 41943040);             //  2,097,152 B
    bf16*  Bt   = (bf16*)(ws + 44040192);             //    524,288 B
    bf16*  Ab   = (bf16*)(ws + 44564480);             //    524,288 B

    prep_kernel<<<384, 256, 0, stream>>>(lora_B, lora_A, Bt, Ab);
    fused_kernel<<<256 + 2048, 256, 0, stream>>>(
        x, gate_w, gate_b, base_w, Ab, Xb, Wb, A2, probs);
    gemm_kernel<<<dim3(64, 16), 256, 0, stream>>>(Xb, Wb, base_b, A2, Bt, out);
}